// Round 1
// baseline (150.708 us; speedup 1.0000x reference)
//
#include <hip/hip_runtime.h>
#include <hip/hip_bf16.h>

#define B_ 8
#define DIN 16
#define L_ 4096
#define D_ 512
#define NP 4104
#define NG 342

__device__ __forceinline__ unsigned short f2bf(float f) {
  unsigned int u = __float_as_uint(f);
  unsigned int r = (u + 0x7fffu + ((u >> 16) & 1u)) >> 16;
  return (unsigned short)r;
}
__device__ __forceinline__ float bf2f(unsigned int u) {
  return __uint_as_float(u << 16);
}

// ---------------- Kernel 1: conv -> h (bf16) ----------------
// h[b,n,d] = conv_b[d] + sum_{i,k} x[b,i,n+k-1] * conv_w[d,i,k]
// block: 256 thr; tile: 32 n x 128 d; thread: 2 consecutive d x 8 n
__global__ __launch_bounds__(256) void k_conv(
    const float* __restrict__ x, const float* __restrict__ cw,
    const float* __restrict__ cb, unsigned short* __restrict__ h) {
  __shared__ float ws_w[64 * 132];   // per d-pair: [0..63] even-d row, [64..127] odd-d row
  __shared__ float ws_x[DIN * 40];   // ws_x[i][c] = x[b,i,n0+c-4]
  int bid = blockIdx.x;
  int dtile = bid & 3;
  int ntile = (bid >> 2) & 127;
  int b = bid >> 9;
  int n0 = ntile * 32;
  int d0 = dtile * 128;
  int tid = threadIdx.x;

  for (int q = tid; q < 128 * 16; q += 256) {
    int dd = q >> 4, qq = (q & 15) << 2;
    float4 wv = *reinterpret_cast<const float4*>(cw + ((size_t)(d0 + dd) << 6) + qq);
    *reinterpret_cast<float4*>(&ws_w[(dd >> 1) * 132 + (dd & 1) * 64 + qq]) = wv;
  }
  const float* xb = x + (size_t)b * DIN * L_;
  for (int q = tid; q < DIN * 40; q += 256) {
    int i = q / 40, c = q - i * 40;
    int nx = n0 + c - 4;
    ws_x[q] = (nx >= 0 && nx < L_) ? xb[i * L_ + nx] : 0.0f;
  }
  __syncthreads();

  int dp = tid & 63;
  int seg = tid >> 6;
  float acc0[8], acc1[8];
#pragma unroll
  for (int j = 0; j < 8; ++j) { acc0[j] = 0.f; acc1[j] = 0.f; }

  for (int i = 0; i < DIN; ++i) {
    const float* wp = &ws_w[dp * 132 + (i << 2)];
    float w00 = wp[0], w01 = wp[1], w02 = wp[2], w03 = wp[3];
    float w10 = wp[64], w11 = wp[65], w12 = wp[66], w13 = wp[67];
    const float* xp = &ws_x[i * 40 + (seg << 3)];
    float xr[16];
#pragma unroll
    for (int m = 0; m < 16; ++m) xr[m] = xp[m];
#pragma unroll
    for (int j = 0; j < 8; ++j) {
      float a0 = acc0[j], a1 = acc1[j];
      a0 = fmaf(w00, xr[j + 3], a0);
      a0 = fmaf(w01, xr[j + 4], a0);
      a0 = fmaf(w02, xr[j + 5], a0);
      a0 = fmaf(w03, xr[j + 6], a0);
      a1 = fmaf(w10, xr[j + 3], a1);
      a1 = fmaf(w11, xr[j + 4], a1);
      a1 = fmaf(w12, xr[j + 5], a1);
      a1 = fmaf(w13, xr[j + 6], a1);
      acc0[j] = a0; acc1[j] = a1;
    }
  }
  int d = d0 + (dp << 1);
  float cb0 = cb[d], cb1 = cb[d + 1];
  unsigned short* hb = h + (size_t)b * L_ * D_;
#pragma unroll
  for (int j = 0; j < 8; ++j) {
    int n = n0 + (seg << 3) + j;
    unsigned int pv = (unsigned int)f2bf(acc0[j] + cb0) |
                      ((unsigned int)f2bf(acc1[j] + cb1) << 16);
    *reinterpret_cast<unsigned int*>(&hb[(size_t)n * D_ + d]) = pv;
  }
}

// ---------------- Kernel 2a: u[i,k] = sum_d sw[d]*cw[d,i,k]; c0 = sum_d sw[d]*cb[d]
__global__ __launch_bounds__(256) void k_uprep(
    const float* __restrict__ cw, const float* __restrict__ cb,
    const float* __restrict__ sw, float* __restrict__ us) {
  __shared__ float red[4][64];
  __shared__ float red2[64];
  int t = threadIdx.x;
  int p = t & 63, chunk = t >> 6;
  float s = 0.f;
  for (int d = chunk * 128; d < chunk * 128 + 128; ++d)
    s = fmaf(sw[d], cw[((size_t)d << 6) + p], s);
  red[chunk][p] = s;
  if (t < 64) {
    float pc = 0.f;
    for (int j = 0; j < 8; ++j) pc = fmaf(sw[t + 64 * j], cb[t + 64 * j], pc);
    red2[t] = pc;
  }
  __syncthreads();
  if (t < 64) us[t] = red[0][t] + red[1][t] + red[2][t] + red[3][t];
  if (t == 0) {
    float c0 = 0.f;
    for (int j = 0; j < 64; ++j) c0 += red2[j];
    us[64] = c0;
  }
}

// ---------------- Kernel 2b: t -> pooled means -> softmax over m -> s0 (bf16)
// block = 192 thr (16 groups of 12); t[n]=0 for n>=L
__global__ __launch_bounds__(192) void k_scores(
    const float* __restrict__ x, const float* __restrict__ us,
    const float* __restrict__ sb, unsigned short* __restrict__ s0) {
  __shared__ float xs[DIN * 195];
  __shared__ float ul[65];
  __shared__ float tb[192];
  int bid = blockIdx.x;
  int b = bid / 22, blk = bid - b * 22;
  int base0 = blk * 192;
  int t = threadIdx.x;
  const float* xb = x + (size_t)b * DIN * L_;
  for (int q = t; q < DIN * 195; q += 192) {
    int i = q / 195, c = q - i * 195;
    int nx = base0 - 1 + c;
    xs[q] = (nx >= 0 && nx < L_) ? xb[i * L_ + nx] : 0.f;
  }
  if (t < 65) ul[t] = us[t];
  __syncthreads();
  int n = base0 + t;
  float tv = 0.f;
  if (n < L_) {
    tv = ul[64];
    for (int i = 0; i < DIN; ++i) {
#pragma unroll
      for (int k = 0; k < 4; ++k)
        tv = fmaf(xs[i * 195 + t + k], ul[(i << 2) + k], tv);
    }
  }
  tb[t] = tv;
  __syncthreads();
  if (n < NP) {
    float t1 = tb[t];
    int e2 = t & ~1;
    float t2 = 0.5f * (tb[e2] + tb[e2 + 1]);
    int e3 = (t / 3) * 3;
    float t3 = (1.f / 3.f) * (tb[e3] + tb[e3 + 1] + tb[e3 + 2]);
    int e4 = t & ~3;
    float t4 = 0.25f * (tb[e4] + tb[e4 + 1] + tb[e4 + 2] + tb[e4 + 3]);
    float sbv = sb[0];
    float c0s = t1 + sbv, c1s = t2 + sbv, c2s = t3 + sbv, c3s = t4 + sbv;
    float mx = fmaxf(fmaxf(c0s, c1s), fmaxf(c2s, c3s));
    float e0 = __expf(c0s - mx), e1 = __expf(c1s - mx);
    float e2f = __expf(c2s - mx), e3f = __expf(c3s - mx);
    float inv = 1.f / (e0 + e1 + e2f + e3f);
    ushort4 ov;
    ov.x = f2bf(e0 * inv); ov.y = f2bf(e1 * inv);
    ov.z = f2bf(e2f * inv); ov.w = f2bf(e3f * inv);
    *reinterpret_cast<ushort4*>(&s0[(((size_t)b * NP) + n) << 2]) = ov;
  }
}

// ---------------- Kernel 3: attention over positions ----------------
// out_i = (sum_j exp(s_i.s_j) s_j) / (sum_j exp(s_i.s_j)); dots in (0,1] so no max-sub
__global__ __launch_bounds__(256) void k_attn(
    const unsigned short* __restrict__ s0, float* __restrict__ s2) {
  __shared__ ushort4 sm[NP];       // 32832 B
  __shared__ float pb[4][64][8];   // 8192 B
  int bid = blockIdx.x;
  int b = bid / 65, chunk = bid - b * 65;
  int t = threadIdx.x;
  const ushort4* sp = reinterpret_cast<const ushort4*>(s0 + (((size_t)b * NP) << 2));
  for (int j = t; j < NP; j += 256) sm[j] = sp[j];
  __syncthreads();
  int il = t & 63, js = t >> 6;
  int i = chunk * 64 + il;
  int iw = (i < NP) ? i : (NP - 1);
  ushort4 siu = sm[iw];
  float si0 = bf2f(siu.x), si1 = bf2f(siu.y), si2 = bf2f(siu.z), si3 = bf2f(siu.w);
  float a0 = 0.f, a1 = 0.f, a2 = 0.f, a3 = 0.f, Z = 0.f;
  int j0 = js * 1026, j1 = j0 + 1026;
  for (int j = j0; j < j1; ++j) {
    ushort4 sj = sm[j];
    float v0 = bf2f(sj.x), v1 = bf2f(sj.y), v2 = bf2f(sj.z), v3 = bf2f(sj.w);
    float dt = si0 * v0;
    dt = fmaf(si1, v1, dt);
    dt = fmaf(si2, v2, dt);
    dt = fmaf(si3, v3, dt);
    float e = __expf(dt);
    a0 = fmaf(e, v0, a0); a1 = fmaf(e, v1, a1);
    a2 = fmaf(e, v2, a2); a3 = fmaf(e, v3, a3);
    Z += e;
  }
  pb[js][il][0] = a0; pb[js][il][1] = a1; pb[js][il][2] = a2;
  pb[js][il][3] = a3; pb[js][il][4] = Z;
  __syncthreads();
  if (js == 0 && i < NP) {
    float b0 = pb[0][il][0] + pb[1][il][0] + pb[2][il][0] + pb[3][il][0];
    float b1 = pb[0][il][1] + pb[1][il][1] + pb[2][il][1] + pb[3][il][1];
    float b2 = pb[0][il][2] + pb[1][il][2] + pb[2][il][2] + pb[3][il][2];
    float b3 = pb[0][il][3] + pb[1][il][3] + pb[2][il][3] + pb[3][il][3];
    float Zt = pb[0][il][4] + pb[1][il][4] + pb[2][il][4] + pb[3][il][4];
    float inv = 1.f / Zt;
    float4 o; o.x = b0 * inv; o.y = b1 * inv; o.z = b2 * inv; o.w = b3 * inv;
    *reinterpret_cast<float4*>(&s2[(((size_t)b * NP) + i) << 2]) = o;
  }
}

// ---------------- Kernel 4: xo + outputs ----------------
// per (b, 12-group): recompute pooled means from h rows, combine with s2,
// write char_x rows (n<L) and fused xd (mean of 4)
__global__ __launch_bounds__(256) void k_final(
    const unsigned short* __restrict__ h, const float* __restrict__ s2,
    float* __restrict__ out) {
  __shared__ float ss[12][4];
  int bid = blockIdx.x;
  int b = bid / NG, g = bid - b * NG;
  int base = g * 12;
  int t = threadIdx.x;
  if (t < 48) ((float*)ss)[t] = s2[((((size_t)b * NP) + base) << 2) + t];
  __syncthreads();
  int d = t << 1;
  const unsigned short* hb = h + (size_t)b * L_ * D_;
  float hv0[12], hv1[12];
#pragma unroll
  for (int j = 0; j < 12; ++j) {
    int n = base + j;
    if (n < L_) {
      unsigned int u = *reinterpret_cast<const unsigned int*>(&hb[(size_t)n * D_ + d]);
      hv0[j] = bf2f(u & 0xffffu); hv1[j] = bf2f(u >> 16);
    } else { hv0[j] = 0.f; hv1[j] = 0.f; }
  }
  float P20[6], P21[6], P30[4], P31[4], P40[3], P41[3];
#pragma unroll
  for (int q = 0; q < 6; ++q) {
    P20[q] = 0.5f * (hv0[2 * q] + hv0[2 * q + 1]);
    P21[q] = 0.5f * (hv1[2 * q] + hv1[2 * q + 1]);
  }
#pragma unroll
  for (int q = 0; q < 4; ++q) {
    P30[q] = (1.f / 3.f) * (hv0[3 * q] + hv0[3 * q + 1] + hv0[3 * q + 2]);
    P31[q] = (1.f / 3.f) * (hv1[3 * q] + hv1[3 * q + 1] + hv1[3 * q + 2]);
  }
#pragma unroll
  for (int q = 0; q < 3; ++q) {
    P40[q] = 0.25f * (hv0[4 * q] + hv0[4 * q + 1] + hv0[4 * q + 2] + hv0[4 * q + 3]);
    P41[q] = 0.25f * (hv1[4 * q] + hv1[4 * q + 1] + hv1[4 * q + 2] + hv1[4 * q + 3]);
  }
  float* outc = out;
  float* outd = out + (size_t)B_ * L_ * D_;
  float xq0[3] = {0.f, 0.f, 0.f}, xq1[3] = {0.f, 0.f, 0.f};
#pragma unroll
  for (int j = 0; j < 12; ++j) {
    float w0 = ss[j][0], w1 = ss[j][1], w2 = ss[j][2], w3 = ss[j][3];
    float v0 = w0 * hv0[j] + w1 * P20[j >> 1] + w2 * P30[j / 3] + w3 * P40[j >> 2];
    float v1 = w0 * hv1[j] + w1 * P21[j >> 1] + w2 * P31[j / 3] + w3 * P41[j >> 2];
    int n = base + j;
    if (n < L_) {
      float2 o; o.x = v0; o.y = v1;
      *reinterpret_cast<float2*>(&outc[((size_t)b * L_ + n) * D_ + d]) = o;
    }
    xq0[j >> 2] += v0; xq1[j >> 2] += v1;
  }
#pragma unroll
  for (int q = 0; q < 3; ++q) {
    int r = 3 * g + q;
    if (r < 1024) {
      float2 o; o.x = 0.25f * xq0[q]; o.y = 0.25f * xq1[q];
      *reinterpret_cast<float2*>(&outd[((size_t)b * 1024 + r) * D_ + d]) = o;
    }
  }
}

extern "C" void kernel_launch(void* const* d_in, const int* in_sizes, int n_in,
                              void* d_out, int out_size, void* d_ws, size_t ws_size,
                              hipStream_t stream) {
  const float* x = (const float*)d_in[0];
  const float* cw = (const float*)d_in[1];
  const float* cb = (const float*)d_in[2];
  const float* sw = (const float*)d_in[3];
  const float* sb = (const float*)d_in[4];
  float* out = (float*)d_out;
  char* ws = (char*)d_ws;
  unsigned short* h = (unsigned short*)ws;                              // 33,554,432 B
  unsigned short* s0 = (unsigned short*)(ws + 33554432);                // 262,656 B
  float* s2 = (float*)(ws + 33554432 + 262656);                         // 525,312 B
  float* us = (float*)(ws + 33554432 + 262656 + 525312);                // 260 B

  k_conv<<<4096, 256, 0, stream>>>(x, cw, cb, h);
  k_uprep<<<1, 256, 0, stream>>>(cw, cb, sw, us);
  k_scores<<<8 * 22, 192, 0, stream>>>(x, us, sb, s0);
  k_attn<<<8 * 65, 256, 0, stream>>>(s0, s2);
  k_final<<<8 * NG, 256, 0, stream>>>(h, s2, out);
}

// Round 2
// 138.023 us; speedup vs baseline: 1.0919x; 1.0919x over previous
//
#include <hip/hip_runtime.h>
#include <hip/hip_bf16.h>

#define B_ 8
#define DIN 16
#define L_ 4096
#define D_ 512
#define NP 4104
#define NG 342
#define JS 513
#define ICH 17
#define IPAD 4352

__device__ __forceinline__ unsigned short f2bf(float f) {
  unsigned int u = __float_as_uint(f);
  unsigned int r = (u + 0x7fffu + ((u >> 16) & 1u)) >> 16;
  return (unsigned short)r;
}
__device__ __forceinline__ float bf2f(unsigned int u) {
  return __uint_as_float(u << 16);
}

// ---------------- Kernel 1: conv -> h (bf16) ----------------
__global__ __launch_bounds__(256) void k_conv(
    const float* __restrict__ x, const float* __restrict__ cw,
    const float* __restrict__ cb, unsigned short* __restrict__ h) {
  __shared__ float ws_w[64 * 132];
  __shared__ float ws_x[DIN * 40];
  int bid = blockIdx.x;
  int dtile = bid & 3;
  int ntile = (bid >> 2) & 127;
  int b = bid >> 9;
  int n0 = ntile * 32;
  int d0 = dtile * 128;
  int tid = threadIdx.x;

  for (int q = tid; q < 128 * 16; q += 256) {
    int dd = q >> 4, qq = (q & 15) << 2;
    float4 wv = *reinterpret_cast<const float4*>(cw + ((size_t)(d0 + dd) << 6) + qq);
    *reinterpret_cast<float4*>(&ws_w[(dd >> 1) * 132 + (dd & 1) * 64 + qq]) = wv;
  }
  const float* xb = x + (size_t)b * DIN * L_;
  for (int q = tid; q < DIN * 40; q += 256) {
    int i = q / 40, c = q - i * 40;
    int nx = n0 + c - 4;
    ws_x[q] = (nx >= 0 && nx < L_) ? xb[i * L_ + nx] : 0.0f;
  }
  __syncthreads();

  int dp = tid & 63;
  int seg = tid >> 6;
  float acc0[8], acc1[8];
#pragma unroll
  for (int j = 0; j < 8; ++j) { acc0[j] = 0.f; acc1[j] = 0.f; }

  for (int i = 0; i < DIN; ++i) {
    const float* wp = &ws_w[dp * 132 + (i << 2)];
    float w00 = wp[0], w01 = wp[1], w02 = wp[2], w03 = wp[3];
    float w10 = wp[64], w11 = wp[65], w12 = wp[66], w13 = wp[67];
    const float* xp = &ws_x[i * 40 + (seg << 3)];
    float xr[16];
#pragma unroll
    for (int m = 0; m < 16; ++m) xr[m] = xp[m];
#pragma unroll
    for (int j = 0; j < 8; ++j) {
      float a0 = acc0[j], a1 = acc1[j];
      a0 = fmaf(w00, xr[j + 3], a0);
      a0 = fmaf(w01, xr[j + 4], a0);
      a0 = fmaf(w02, xr[j + 5], a0);
      a0 = fmaf(w03, xr[j + 6], a0);
      a1 = fmaf(w10, xr[j + 3], a1);
      a1 = fmaf(w11, xr[j + 4], a1);
      a1 = fmaf(w12, xr[j + 5], a1);
      a1 = fmaf(w13, xr[j + 6], a1);
      acc0[j] = a0; acc1[j] = a1;
    }
  }
  int d = d0 + (dp << 1);
  float cb0 = cb[d], cb1 = cb[d + 1];
  unsigned short* hb = h + (size_t)b * L_ * D_;
#pragma unroll
  for (int j = 0; j < 8; ++j) {
    int n = n0 + (seg << 3) + j;
    unsigned int pv = (unsigned int)f2bf(acc0[j] + cb0) |
                      ((unsigned int)f2bf(acc1[j] + cb1) << 16);
    *reinterpret_cast<unsigned int*>(&hb[(size_t)n * D_ + d]) = pv;
  }
}

// ---------------- Kernel 2a: u prep ----------------
__global__ __launch_bounds__(256) void k_uprep(
    const float* __restrict__ cw, const float* __restrict__ cb,
    const float* __restrict__ sw, float* __restrict__ us) {
  __shared__ float red[4][64];
  __shared__ float red2[64];
  int t = threadIdx.x;
  int p = t & 63, chunk = t >> 6;
  float s = 0.f;
  for (int d = chunk * 128; d < chunk * 128 + 128; ++d)
    s = fmaf(sw[d], cw[((size_t)d << 6) + p], s);
  red[chunk][p] = s;
  if (t < 64) {
    float pc = 0.f;
    for (int j = 0; j < 8; ++j) pc = fmaf(sw[t + 64 * j], cb[t + 64 * j], pc);
    red2[t] = pc;
  }
  __syncthreads();
  if (t < 64) us[t] = red[0][t] + red[1][t] + red[2][t] + red[3][t];
  if (t == 0) {
    float c0 = 0.f;
    for (int j = 0; j < 64; ++j) c0 += red2[j];
    us[64] = c0;
  }
}

// ---------------- Kernel 2b: scores -> softmax over m -> s0 (bf16) ----------------
__global__ __launch_bounds__(192) void k_scores(
    const float* __restrict__ x, const float* __restrict__ us,
    const float* __restrict__ sb, unsigned short* __restrict__ s0) {
  __shared__ float xs[DIN * 195];
  __shared__ float ul[65];
  __shared__ float tb[192];
  int bid = blockIdx.x;
  int b = bid / 22, blk = bid - b * 22;
  int base0 = blk * 192;
  int t = threadIdx.x;
  const float* xb = x + (size_t)b * DIN * L_;
  for (int q = t; q < DIN * 195; q += 192) {
    int i = q / 195, c = q - i * 195;
    int nx = base0 - 1 + c;
    xs[q] = (nx >= 0 && nx < L_) ? xb[i * L_ + nx] : 0.f;
  }
  if (t < 65) ul[t] = us[t];
  __syncthreads();
  int n = base0 + t;
  float tv = 0.f;
  if (n < L_) {
    tv = ul[64];
    for (int i = 0; i < DIN; ++i) {
#pragma unroll
      for (int k = 0; k < 4; ++k)
        tv = fmaf(xs[i * 195 + t + k], ul[(i << 2) + k], tv);
    }
  }
  tb[t] = tv;
  __syncthreads();
  if (n < NP) {
    float t1 = tb[t];
    int e2 = t & ~1;
    float t2 = 0.5f * (tb[e2] + tb[e2 + 1]);
    int e3 = (t / 3) * 3;
    float t3 = (1.f / 3.f) * (tb[e3] + tb[e3 + 1] + tb[e3 + 2]);
    int e4 = t & ~3;
    float t4 = 0.25f * (tb[e4] + tb[e4 + 1] + tb[e4 + 2] + tb[e4 + 3]);
    float sbv = sb[0];
    float c0s = t1 + sbv, c1s = t2 + sbv, c2s = t3 + sbv, c3s = t4 + sbv;
    float mx = fmaxf(fmaxf(c0s, c1s), fmaxf(c2s, c3s));
    float e0 = __expf(c0s - mx), e1 = __expf(c1s - mx);
    float e2f = __expf(c2s - mx), e3f = __expf(c3s - mx);
    float inv = 1.f / (e0 + e1 + e2f + e3f);
    ushort4 ov;
    ov.x = f2bf(e0 * inv); ov.y = f2bf(e1 * inv);
    ov.z = f2bf(e2f * inv); ov.w = f2bf(e3f * inv);
    *reinterpret_cast<ushort4*>(&s0[(((size_t)b * NP) + n) << 2]) = ov;
  }
}

// ---------------- Kernel 3: attention, partial over j-slices ----------------
// grid: b(8) x ichunk(17) x jsplit(8). thread t owns row i = ic*256+t.
// partial: pa[(b*8+js)*IPAD + i] = sum_j exp(si.sj) * sj ; pz likewise Z.
__global__ __launch_bounds__(256) void k_attn(
    const unsigned short* __restrict__ s0, float4* __restrict__ pa,
    float* __restrict__ pz) {
  __shared__ float4 sm[JS];
  int bid = blockIdx.x;
  int js = bid & 7;
  int ic = (bid >> 3) % ICH;
  int b = bid / (ICH * 8);
  int t = threadIdx.x;
  const ushort4* sp = reinterpret_cast<const ushort4*>(s0) + (size_t)b * NP;
  for (int q = t; q < JS; q += 256) {
    ushort4 u = sp[js * JS + q];
    float4 f;
    f.x = bf2f(u.x); f.y = bf2f(u.y); f.z = bf2f(u.z); f.w = bf2f(u.w);
    sm[q] = f;
  }
  __syncthreads();
  int i = ic * 256 + t;
  int iw = (i < NP) ? i : (NP - 1);
  ushort4 su = sp[iw];
  const float RLN2 = 1.44269504088896341f;  // log2(e)
  float si0 = bf2f(su.x) * RLN2, si1 = bf2f(su.y) * RLN2;
  float si2 = bf2f(su.z) * RLN2, si3 = bf2f(su.w) * RLN2;
  float a0 = 0.f, a1 = 0.f, a2 = 0.f, a3 = 0.f, Z = 0.f;
#pragma unroll 4
  for (int j = 0; j < JS; ++j) {
    float4 v = sm[j];
    float dt = si0 * v.x;
    dt = fmaf(si1, v.y, dt);
    dt = fmaf(si2, v.z, dt);
    dt = fmaf(si3, v.w, dt);
    float e = exp2f(dt);
    a0 = fmaf(e, v.x, a0);
    a1 = fmaf(e, v.y, a1);
    a2 = fmaf(e, v.z, a2);
    a3 = fmaf(e, v.w, a3);
    Z += e;
  }
  size_t p = ((size_t)(b * 8 + js)) * IPAD + i;
  pa[p] = make_float4(a0, a1, a2, a3);
  pz[p] = Z;
}

// ---------------- Kernel 3b: reduce partials -> s2 ----------------
__global__ __launch_bounds__(256) void k_attn_red(
    const float4* __restrict__ pa, const float* __restrict__ pz,
    float* __restrict__ s2) {
  int idx = blockIdx.x * 256 + threadIdx.x;
  if (idx >= B_ * NP) return;
  int b = idx / NP, i = idx - b * NP;
  float a0 = 0.f, a1 = 0.f, a2 = 0.f, a3 = 0.f, Z = 0.f;
#pragma unroll
  for (int js = 0; js < 8; ++js) {
    size_t p = ((size_t)(b * 8 + js)) * IPAD + i;
    float4 v = pa[p];
    a0 += v.x; a1 += v.y; a2 += v.z; a3 += v.w;
    Z += pz[p];
  }
  float inv = 1.f / Z;
  reinterpret_cast<float4*>(s2)[(size_t)b * NP + i] =
      make_float4(a0 * inv, a1 * inv, a2 * inv, a3 * inv);
}

// ---------------- Kernel 4: xo + outputs ----------------
__global__ __launch_bounds__(256) void k_final(
    const unsigned short* __restrict__ h, const float* __restrict__ s2,
    float* __restrict__ out) {
  __shared__ float ss[12][4];
  int bid = blockIdx.x;
  int b = bid / NG, g = bid - b * NG;
  int base = g * 12;
  int t = threadIdx.x;
  if (t < 48) ((float*)ss)[t] = s2[((((size_t)b * NP) + base) << 2) + t];
  __syncthreads();
  int d = t << 1;
  const unsigned short* hb = h + (size_t)b * L_ * D_;
  float hv0[12], hv1[12];
#pragma unroll
  for (int j = 0; j < 12; ++j) {
    int n = base + j;
    if (n < L_) {
      unsigned int u = *reinterpret_cast<const unsigned int*>(&hb[(size_t)n * D_ + d]);
      hv0[j] = bf2f(u & 0xffffu); hv1[j] = bf2f(u >> 16);
    } else { hv0[j] = 0.f; hv1[j] = 0.f; }
  }
  float P20[6], P21[6], P30[4], P31[4], P40[3], P41[3];
#pragma unroll
  for (int q = 0; q < 6; ++q) {
    P20[q] = 0.5f * (hv0[2 * q] + hv0[2 * q + 1]);
    P21[q] = 0.5f * (hv1[2 * q] + hv1[2 * q + 1]);
  }
#pragma unroll
  for (int q = 0; q < 4; ++q) {
    P30[q] = (1.f / 3.f) * (hv0[3 * q] + hv0[3 * q + 1] + hv0[3 * q + 2]);
    P31[q] = (1.f / 3.f) * (hv1[3 * q] + hv1[3 * q + 1] + hv1[3 * q + 2]);
  }
#pragma unroll
  for (int q = 0; q < 3; ++q) {
    P40[q] = 0.25f * (hv0[4 * q] + hv0[4 * q + 1] + hv0[4 * q + 2] + hv0[4 * q + 3]);
    P41[q] = 0.25f * (hv1[4 * q] + hv1[4 * q + 1] + hv1[4 * q + 2] + hv1[4 * q + 3]);
  }
  float* outc = out;
  float* outd = out + (size_t)B_ * L_ * D_;
  float xq0[3] = {0.f, 0.f, 0.f}, xq1[3] = {0.f, 0.f, 0.f};
#pragma unroll
  for (int j = 0; j < 12; ++j) {
    float w0 = ss[j][0], w1 = ss[j][1], w2 = ss[j][2], w3 = ss[j][3];
    float v0 = w0 * hv0[j] + w1 * P20[j >> 1] + w2 * P30[j / 3] + w3 * P40[j >> 2];
    float v1 = w0 * hv1[j] + w1 * P21[j >> 1] + w2 * P31[j / 3] + w3 * P41[j >> 2];
    int n = base + j;
    if (n < L_) {
      float2 o; o.x = v0; o.y = v1;
      *reinterpret_cast<float2*>(&outc[((size_t)b * L_ + n) * D_ + d]) = o;
    }
    xq0[j >> 2] += v0; xq1[j >> 2] += v1;
  }
#pragma unroll
  for (int q = 0; q < 3; ++q) {
    int r = 3 * g + q;
    if (r < 1024) {
      float2 o; o.x = 0.25f * xq0[q]; o.y = 0.25f * xq1[q];
      *reinterpret_cast<float2*>(&outd[((size_t)b * 1024 + r) * D_ + d]) = o;
    }
  }
}

extern "C" void kernel_launch(void* const* d_in, const int* in_sizes, int n_in,
                              void* d_out, int out_size, void* d_ws, size_t ws_size,
                              hipStream_t stream) {
  const float* x = (const float*)d_in[0];
  const float* cw = (const float*)d_in[1];
  const float* cb = (const float*)d_in[2];
  const float* sw = (const float*)d_in[3];
  const float* sb = (const float*)d_in[4];
  float* out = (float*)d_out;
  char* ws = (char*)d_ws;
  unsigned short* h = (unsigned short*)ws;                 // 33,554,432 B
  size_t off = 33554432;
  unsigned short* s0 = (unsigned short*)(ws + off);        // 262,656 B
  off += 262656;
  float* s2 = (float*)(ws + off);                          // 525,312 B
  off += 525312;
  float4* pa = (float4*)(ws + off);                        // 8*8*4352*16 = 4,456,448 B
  off += (size_t)B_ * 8 * IPAD * 16;
  float* pz = (float*)(ws + off);                          // 1,114,112 B
  off += (size_t)B_ * 8 * IPAD * 4;
  float* us = (float*)(ws + off);                          // 260 B

  k_conv<<<4096, 256, 0, stream>>>(x, cw, cb, h);
  k_uprep<<<1, 256, 0, stream>>>(cw, cb, sw, us);
  k_scores<<<8 * 22, 192, 0, stream>>>(x, us, sb, s0);
  k_attn<<<B_ * ICH * 8, 256, 0, stream>>>(s0, pa, pz);
  k_attn_red<<<(B_ * NP + 255) / 256, 256, 0, stream>>>(pa, pz, s2);
  k_final<<<B_ * NG, 256, 0, stream>>>(h, s2, out);
}